// Round 2
// baseline (184.754 us; speedup 1.0000x reference)
//
#include <hip/hip_runtime.h>

// ---------------- geometry ----------------
#define NTOK 49      // tokens per window
#define DIMC 128
#define NH   4
#define HD   32
#define NWIN 64
#define NBLK 4096    // B_ = BATCH * NW

// ws layout (bytes):
//   wqkv  : bf16[4*24*64*8]   = 49152 el -> 98304 B  @ 0
//   wproj : bf16[4*8*64*8]    = 16384 el -> 32768 B  @ 98304
//   bm    : f32 [64*4*2401]   = 614656 el -> 2458624 B @ 131072
#define WPROJ_OFF 98304
#define BM_OFF    131072

typedef unsigned short u16x8 __attribute__((ext_vector_type(8)));
typedef __bf16        bf16x8 __attribute__((ext_vector_type(8)));
typedef float         f32x4  __attribute__((ext_vector_type(4)));

__device__ __forceinline__ unsigned short f2bf(float f) {
  unsigned int u = __float_as_uint(f);
  u += 0x7fffu + ((u >> 16) & 1u);
  return (unsigned short)(u >> 16);
}

__device__ __forceinline__ bf16x8 ld_frag(const unsigned short* p) {
  return __builtin_bit_cast(bf16x8, *(const u16x8*)p);
}

#define MFMA(a, b, c) __builtin_amdgcn_mfma_f32_16x16x32_bf16(a, b, c, 0, 0, 0)

// ---------------- prep: pack weights + fuse mask/bias ----------------
__global__ void prep_kernel(const float* __restrict__ qkv_w,      // [128][384]
                            const float* __restrict__ proj_w,     // [128][128]
                            const float* __restrict__ bias_table, // [169][4]
                            const int*   __restrict__ rel_idx,    // [49*49]
                            const float* __restrict__ mask,       // [64][49][49]
                            unsigned short* __restrict__ wqkv,
                            unsigned short* __restrict__ wproj,
                            float* __restrict__ bm)
{
  const int tid = blockIdx.x * blockDim.x + threadIdx.x;
  const int nth = gridDim.x * blockDim.x;

  for (int idx = tid; idx < 4*24*64*8; idx += nth) {
    int ii = idx & 7, lane = (idx >> 3) & 63, rest = idx >> 9;
    int ct = rest % 24, kt = rest / 24;
    int k = kt*32 + ((lane >> 4) << 3) + ii;
    int c = ct*16 + (lane & 15);
    wqkv[idx] = f2bf(qkv_w[k*384 + c]);
  }
  for (int idx = tid; idx < 4*8*64*8; idx += nth) {
    int ii = idx & 7, lane = (idx >> 3) & 63, rest = idx >> 9;
    int ct = rest & 7, kt = rest >> 3;
    int k = kt*32 + ((lane >> 4) << 3) + ii;
    int c = ct*16 + (lane & 15);
    wproj[idx] = f2bf(proj_w[k*128 + c]);
  }
  for (int idx = tid; idx < NWIN*NH*NTOK*NTOK; idx += nth) {
    int nm = idx % 2401;
    int rest = idx / 2401;
    int h = rest & 3, wi = rest >> 2;
    bm[idx] = mask[wi*2401 + nm] + bias_table[rel_idx[nm]*4 + h];
  }
}

// ---------------- fused window attention (wave == head) ----------------
// LDS (u16 elements), 27136 el = 54272 B -> 3 blocks/CU (12 waves):
//   @0     : xs [64][136] = 8704     (x staging)   --later--> Vt: 4 x [32][68]
//   @8704  : per-head slot h*4608 : Q[64][36] | K[64][36]
//            --later--> P[64][72] (exact alias)  --later--> xo[64][36]
__global__ __launch_bounds__(256, 3) void winattn_kernel(
    const float* __restrict__ x,
    const float* __restrict__ qkv_b,
    const float* __restrict__ proj_b,
    const unsigned short* __restrict__ wqkv,
    const unsigned short* __restrict__ wproj,
    const float* __restrict__ bm,
    float* __restrict__ out)
{
  __shared__ __align__(16) unsigned short smem[27136];
  unsigned short* xs     = smem;          // x staging / later Vt
  unsigned short* qkbase = smem + 8704;   // per-head Q|K / P / xo

  const int b    = blockIdx.x;
  const int wi   = b & (NWIN - 1);
  const int tid  = threadIdx.x;
  const int h    = tid >> 6;    // wave == head
  const int lane = tid & 63;
  const int lhi  = lane >> 4;   // 0..3
  const int llo  = lane & 15;   // 0..15

  // ---- load x -> xs (bf16), zero pad rows 49..63 ----
  {
    const float4* xv = (const float4*)(x + (size_t)b * (NTOK*DIMC));
    for (int idx = tid; idx < 64*32; idx += 256) {
      int n = idx >> 5, c4 = (idx & 31) << 2;
      float4 v = make_float4(0.f, 0.f, 0.f, 0.f);
      if (n < NTOK) v = xv[n*32 + (idx & 31)];
      unsigned short* p = xs + n*136 + c4;
      p[0] = f2bf(v.x); p[1] = f2bf(v.y); p[2] = f2bf(v.z); p[3] = f2bf(v.w);
    }
  }
  __syncthreads();

  unsigned short* Qh  = qkbase + h*4608;  // [64][36]
  unsigned short* Kh  = Qh + 2304;        // [64][36]
  unsigned short* Vh  = xs + h*2176;      // [32][68]  (aliases xs after barrier 2)
  unsigned short* Ph  = Qh;               // [64][72]  (aliases Q|K)
  unsigned short* XOh = Qh;               // [64][36]  (aliases P after PV)

  const f32x4 zv = {0.f, 0.f, 0.f, 0.f};

  // ---- QKV GEMM: wave h computes its head's q,k,v columns ----
  f32x4 acc[6][4];       // [j][i]; j: 0,1=q  2,3=k  4,5=v (16-col tiles)
  #pragma unroll
  for (int j = 0; j < 6; j++)
    #pragma unroll
    for (int i = 0; i < 4; i++) acc[j][i] = zv;

  #pragma unroll
  for (int kt = 0; kt < 4; kt++) {
    bf16x8 a[4];
    #pragma unroll
    for (int i = 0; i < 4; i++)
      a[i] = ld_frag(xs + (i*16 + llo)*136 + kt*32 + lhi*8);
    #pragma unroll
    for (int j = 0; j < 6; j++) {
      int ct = (j >> 1)*8 + h*2 + (j & 1);
      bf16x8 bw = ld_frag(wqkv + (((kt*24 + ct)*64 + lane) << 3));
      #pragma unroll
      for (int i = 0; i < 4; i++) acc[j][i] = MFMA(a[i], bw, acc[j][i]);
    }
  }

  float bias[6];
  #pragma unroll
  for (int j = 0; j < 6; j++)
    bias[j] = qkv_b[((j >> 1)*8 + h*2 + (j & 1))*16 + llo];

  const float scale = 0.17677669529663687f;  // 32^-0.5

  // Q, K epilogue (own slot; before barrier is fine)
  #pragma unroll
  for (int j = 0; j < 2; j++) {
    int d = j*16 + llo;
    #pragma unroll
    for (int i = 0; i < 4; i++)
      #pragma unroll
      for (int r2 = 0; r2 < 4; r2++) {
        int r = i*16 + lhi*4 + r2;
        Qh[r*36 + d] = f2bf((acc[j][i][r2] + bias[j]) * scale);
      }
  }
  #pragma unroll
  for (int j = 2; j < 4; j++) {
    int d = (j - 2)*16 + llo;
    #pragma unroll
    for (int i = 0; i < 4; i++)
      #pragma unroll
      for (int r2 = 0; r2 < 4; r2++) {
        int r = i*16 + lhi*4 + r2;
        Kh[r*36 + d] = f2bf(acc[j][i][r2] + bias[j]);
      }
  }

  __syncthreads();   // all waves done reading xs -> Vt may overwrite it

  // V epilogue -> Vt[d][r], packed 4 consecutive rows per lane (b64 store)
  #pragma unroll
  for (int j = 4; j < 6; j++) {
    int d = (j - 4)*16 + llo;
    #pragma unroll
    for (int i = 0; i < 4; i++) {
      ushort4 pk;
      pk.x = f2bf(acc[j][i][0] + bias[j]);
      pk.y = f2bf(acc[j][i][1] + bias[j]);
      pk.z = f2bf(acc[j][i][2] + bias[j]);
      pk.w = f2bf(acc[j][i][3] + bias[j]);
      *(ushort4*)(Vh + d*68 + i*16 + lhi*4) = pk;
    }
  }

  // ---- QK^T (wave-private, no barrier needed: per-wave DS ops are in-order) ----
  f32x4 s[4][4];
  #pragma unroll
  for (int i = 0; i < 4; i++)
    #pragma unroll
    for (int j = 0; j < 4; j++) s[i][j] = zv;

  {
    bf16x8 qa[4];
    #pragma unroll
    for (int i = 0; i < 4; i++) qa[i] = ld_frag(Qh + (i*16 + llo)*36 + lhi*8);
    #pragma unroll
    for (int j = 0; j < 4; j++) {
      bf16x8 kb = ld_frag(Kh + (j*16 + llo)*36 + lhi*8);
      #pragma unroll
      for (int i = 0; i < 4; i++) s[i][j] = MFMA(qa[i], kb, s[i][j]);
    }
  }

  // ---- + (mask + rel-pos bias), pad -> -1e30 ----
  const float* bmp = bm + (size_t)(wi*4 + h) * 2401;
  #pragma unroll
  for (int i = 0; i < 4; i++) {
    #pragma unroll
    for (int r2 = 0; r2 < 4; r2++) {
      int r = i*16 + lhi*4 + r2;
      #pragma unroll
      for (int j = 0; j < 4; j++) {
        int c = j*16 + llo;
        float v = s[i][j][r2];
        v = (r < NTOK && c < NTOK) ? v + bmp[r*49 + c] : -1e30f;
        s[i][j][r2] = v;
      }
    }
  }

  // ---- row softmax (row = 16 llo lanes x 4 j-regs) ----
  #pragma unroll
  for (int i = 0; i < 4; i++) {
    #pragma unroll
    for (int r2 = 0; r2 < 4; r2++) {
      float m = fmaxf(fmaxf(s[i][0][r2], s[i][1][r2]),
                      fmaxf(s[i][2][r2], s[i][3][r2]));
      #pragma unroll
      for (int off = 1; off < 16; off <<= 1) m = fmaxf(m, __shfl_xor(m, off, 64));
      float sum = 0.f;
      #pragma unroll
      for (int j = 0; j < 4; j++) {
        float p = __expf(s[i][j][r2] - m);
        s[i][j][r2] = p;
        sum += p;
      }
      #pragma unroll
      for (int off = 1; off < 16; off <<= 1) sum += __shfl_xor(sum, off, 64);
      float inv = 1.0f / sum;
      #pragma unroll
      for (int j = 0; j < 4; j++) s[i][j][r2] *= inv;
    }
  }

  // ---- P -> LDS (aliases own Q|K slot; wave-private) ----
  #pragma unroll
  for (int i = 0; i < 4; i++)
    #pragma unroll
    for (int r2 = 0; r2 < 4; r2++) {
      int r = i*16 + lhi*4 + r2;
      #pragma unroll
      for (int j = 0; j < 4; j++)
        Ph[r*72 + j*16 + llo] = f2bf(s[i][j][r2]);
    }

  // ---- PV: O[64][32] = P[64][64] @ V[64][32] ----
  f32x4 oacc[2][4];
  #pragma unroll
  for (int nt = 0; nt < 2; nt++)
    #pragma unroll
    for (int i = 0; i < 4; i++) oacc[nt][i] = zv;

  #pragma unroll
  for (int ks = 0; ks < 2; ks++) {
    bf16x8 pa[4];
    #pragma unroll
    for (int i = 0; i < 4; i++)
      pa[i] = ld_frag(Ph + (i*16 + llo)*72 + ks*32 + lhi*8);
    #pragma unroll
    for (int nt = 0; nt < 2; nt++) {
      bf16x8 vb = ld_frag(Vh + (nt*16 + llo)*68 + ks*32 + lhi*8);
      #pragma unroll
      for (int i = 0; i < 4; i++) oacc[nt][i] = MFMA(pa[i], vb, oacc[nt][i]);
    }
  }

  // ---- attn-out -> xo (own slot, head-major layout for proj) ----
  #pragma unroll
  for (int nt = 0; nt < 2; nt++)
    #pragma unroll
    for (int i = 0; i < 4; i++)
      #pragma unroll
      for (int r2 = 0; r2 < 4; r2++) {
        int r = i*16 + lhi*4 + r2;
        XOh[r*36 + nt*16 + llo] = f2bf(oacc[nt][i][r2]);
      }

  __syncthreads();   // all heads' xo visible

  // ---- proj: out[64][128] = xo @ proj_w + proj_b ; wave h -> cols [h*32,+32) ----
  {
    f32x4 pacc[2][4];
    #pragma unroll
    for (int j = 0; j < 2; j++)
      #pragma unroll
      for (int i = 0; i < 4; i++) pacc[j][i] = zv;

    #pragma unroll
    for (int kt = 0; kt < 4; kt++) {
      bf16x8 a[4];
      #pragma unroll
      for (int i = 0; i < 4; i++)
        a[i] = ld_frag(qkbase + kt*4608 + (i*16 + llo)*36 + lhi*8);
      #pragma unroll
      for (int j = 0; j < 2; j++) {
        int ct = h*2 + j;
        bf16x8 bw = ld_frag(wproj + (((kt*8 + ct)*64 + lane) << 3));
        #pragma unroll
        for (int i = 0; i < 4; i++) pacc[j][i] = MFMA(a[i], bw, pacc[j][i]);
      }
    }

    float* op = out + (size_t)b * (NTOK*DIMC);
    #pragma unroll
    for (int j = 0; j < 2; j++) {
      int c = (h*2 + j)*16 + llo;
      float pb = proj_b[c];
      #pragma unroll
      for (int i = 0; i < 4; i++)
        #pragma unroll
        for (int r2 = 0; r2 < 4; r2++) {
          int r = i*16 + lhi*4 + r2;
          if (r < NTOK) op[r*128 + c] = pacc[j][i][r2] + pb;
        }
    }
  }
}

extern "C" void kernel_launch(void* const* d_in, const int* in_sizes, int n_in,
                              void* d_out, int out_size, void* d_ws, size_t ws_size,
                              hipStream_t stream)
{
  const float* x          = (const float*)d_in[0];
  const float* mask       = (const float*)d_in[1];
  const float* qkv_w      = (const float*)d_in[2];
  const float* qkv_b      = (const float*)d_in[3];
  const float* proj_w     = (const float*)d_in[4];
  const float* proj_b     = (const float*)d_in[5];
  const float* bias_table = (const float*)d_in[6];
  const int*   rel_idx    = (const int*)d_in[7];
  float* out = (float*)d_out;

  unsigned short* wqkv  = (unsigned short*)d_ws;
  unsigned short* wproj = (unsigned short*)((char*)d_ws + WPROJ_OFF);
  float*          bm    = (float*)((char*)d_ws + BM_OFF);

  prep_kernel<<<192, 256, 0, stream>>>(qkv_w, proj_w, bias_table, rel_idx, mask,
                                       wqkv, wproj, bm);
  winattn_kernel<<<NBLK, 256, 0, stream>>>(x, qkv_b, proj_b, wqkv, wproj, bm, out);
}

// Round 3
// 129.725 us; speedup vs baseline: 1.4242x; 1.4242x over previous
//
#include <hip/hip_runtime.h>

// ---------------- geometry ----------------
#define NTOK 49      // tokens per window
#define DIMC 128
#define NH   4
#define NWIN 64
#define NBLK 4096    // B_ = BATCH * NW

// ws layout (bytes):
//   wqkv : bf16[4*24*64*8] = 49152 el -> 98304 B @ 0
//   wproj: bf16[4*8*64*8]  = 16384 el -> 32768 B @ 98304
//   bmf  : f32 [64*4*16*256] = 1048576 el -> 4 MB @ 131072
//          fragment-ordered mask+bias, -1e30 baked for r>=49||c>=49
#define WPROJ_OFF 98304
#define BMF_OFF   131072

typedef unsigned short u16x8 __attribute__((ext_vector_type(8)));
typedef __bf16        bf16x8 __attribute__((ext_vector_type(8)));
typedef float         f32x4  __attribute__((ext_vector_type(4)));

__device__ __forceinline__ unsigned short f2bf(float f) {
  return __builtin_bit_cast(unsigned short, (__bf16)f);   // hw RNE cvt
}

__device__ __forceinline__ bf16x8 ld_frag(const unsigned short* p) {
  return __builtin_bit_cast(bf16x8, *(const u16x8*)p);
}

__device__ __forceinline__ bf16x8 pack_bf16x8(float4 lo, float4 hi) {
  bf16x8 r;
  r[0] = (__bf16)lo.x; r[1] = (__bf16)lo.y; r[2] = (__bf16)lo.z; r[3] = (__bf16)lo.w;
  r[4] = (__bf16)hi.x; r[5] = (__bf16)hi.y; r[6] = (__bf16)hi.z; r[7] = (__bf16)hi.w;
  return r;
}

#define MFMA(a, b, c) __builtin_amdgcn_mfma_f32_16x16x32_bf16(a, b, c, 0, 0, 0)

// ---------------- prep: pack weights + fragment-ordered mask/bias ----------------
__global__ void prep_kernel(const float* __restrict__ qkv_w,      // [128][384]
                            const float* __restrict__ proj_w,     // [128][128]
                            const float* __restrict__ bias_table, // [169][4]
                            const int*   __restrict__ rel_idx,    // [49*49]
                            const float* __restrict__ mask,       // [64][49][49]
                            unsigned short* __restrict__ wqkv,
                            unsigned short* __restrict__ wproj,
                            float* __restrict__ bmf)
{
  const int tid = blockIdx.x * blockDim.x + threadIdx.x;
  const int nth = gridDim.x * blockDim.x;

  for (int idx = tid; idx < 4*24*64*8; idx += nth) {
    int ii = idx & 7, lane = (idx >> 3) & 63, rest = idx >> 9;
    int ct = rest % 24, kt = rest / 24;
    int k = kt*32 + ((lane >> 4) << 3) + ii;
    int c = ct*16 + (lane & 15);
    wqkv[idx] = f2bf(qkv_w[k*384 + c]);
  }
  for (int idx = tid; idx < 4*8*64*8; idx += nth) {
    int ii = idx & 7, lane = (idx >> 3) & 63, rest = idx >> 9;
    int ct = rest & 7, kt = rest >> 3;
    int k = kt*32 + ((lane >> 4) << 3) + ii;
    int c = ct*16 + (lane & 15);
    wproj[idx] = f2bf(proj_w[k*128 + c]);
  }
  // bmf[(((wi*4+h)*16 + i*4+j)*64 + lane)*4 + r2]
  for (int idx = tid; idx < NWIN*NH*16*256; idx += nth) {
    int r2   = idx & 3;
    int lane = (idx >> 2) & 63;
    int ij   = (idx >> 8) & 15;
    int h    = (idx >> 12) & 3;
    int wi   = idx >> 14;
    int i = ij >> 2, j = ij & 3;
    int r = i*16 + ((lane >> 4) << 2) + r2;
    int c = j*16 + (lane & 15);
    float v = -1e30f;
    if (r < NTOK && c < NTOK)
      v = mask[wi*2401 + r*49 + c] + bias_table[rel_idx[r*49 + c]*4 + h];
    bmf[idx] = v;
  }
}

// ---------------- fused window attention (wave == head) ----------------
// LDS: 4 slots x 5712 u16 = 22848 el = 45696 B -> 3 blocks/CU.
// slot: Q[49][36] @0 | K[49][36] @1764 | Vt[32][68] @3528
//   P[<49][72] aliases Q|K exactly (writes r<49 stay < 3528)
//   xo[<49][36] aliases P after PV
// Reads of "rows 49..63" intentionally hit adjacent in-slot garbage:
//   - K cols >=49 -> replaced by cndmask(-1e30) (NaN-proof)
//   - Q/P/xo rows >=49 -> output rows discarded by store predicates
//   - Vt cols are written for all 64 tokens (finite) so PV sees no NaN
#define SLOT 5712
__global__ __launch_bounds__(256, 3) void winattn_kernel(
    const float* __restrict__ x,
    const float* __restrict__ qkv_b,
    const float* __restrict__ proj_b,
    const unsigned short* __restrict__ wqkv,
    const unsigned short* __restrict__ wproj,
    const float* __restrict__ bmf,
    float* __restrict__ out)
{
  __shared__ __align__(16) unsigned short smem[4*SLOT];

  const int b    = blockIdx.x;
  const int wi   = b & (NWIN - 1);
  const int tid  = threadIdx.x;
  const int h    = tid >> 6;    // wave == head
  const int lane = tid & 63;
  const int lhi  = lane >> 4;   // 0..3
  const int llo  = lane & 15;   // 0..15

  unsigned short* slot = smem + h*SLOT;
  unsigned short* Qh  = slot;          // [49][36]
  unsigned short* Kh  = slot + 1764;   // [49][36]
  unsigned short* Vh  = slot + 3528;   // [32][68]
  unsigned short* Ph  = slot;          // [<49][72]
  unsigned short* XOh = slot;          // [<49][36]

  const f32x4 zv = {0.f, 0.f, 0.f, 0.f};
  const float* xb = x + (size_t)b * (NTOK*DIMC);

  // ---- QKV GEMM: A-frags straight from global (f32 -> bf16 in-register) ----
  f32x4 acc[6][4];   // j: 0,1=q  2,3=k  4,5=v
  #pragma unroll
  for (int j = 0; j < 6; j++)
    #pragma unroll
    for (int i = 0; i < 4; i++) acc[j][i] = zv;

  #pragma unroll
  for (int kt = 0; kt < 4; kt++) {
    bf16x8 a[4];
    #pragma unroll
    for (int i = 0; i < 4; i++) {
      float4 lo = make_float4(0.f,0.f,0.f,0.f), hi = lo;
      int row = i*16 + llo;
      if (i < 3 || row < NTOK) {                 // i<3 always in-range
        const float4* p = (const float4*)(xb + row*DIMC + kt*32 + lhi*8);
        lo = p[0]; hi = p[1];
      }
      a[i] = pack_bf16x8(lo, hi);
    }
    #pragma unroll
    for (int j = 0; j < 6; j++) {
      int ct = (j >> 1)*8 + h*2 + (j & 1);
      bf16x8 bw = ld_frag(wqkv + (((kt*24 + ct)*64 + lane) << 3));
      #pragma unroll
      for (int i = 0; i < 4; i++) acc[j][i] = MFMA(a[i], bw, acc[j][i]);
    }
  }

  float bias[6];
  #pragma unroll
  for (int j = 0; j < 6; j++)
    bias[j] = qkv_b[((j >> 1)*8 + h*2 + (j & 1))*16 + llo];

  const float scale = 0.17677669529663687f;  // 32^-0.5

  // Q epilogue (rows < 49 only — slot is 49 rows)
  #pragma unroll
  for (int j = 0; j < 2; j++) {
    int d = j*16 + llo;
    #pragma unroll
    for (int i = 0; i < 4; i++)
      #pragma unroll
      for (int r2 = 0; r2 < 4; r2++) {
        int r = i*16 + lhi*4 + r2;
        if (r < NTOK) Qh[r*36 + d] = f2bf((acc[j][i][r2] + bias[j]) * scale);
      }
  }
  // K epilogue
  #pragma unroll
  for (int j = 2; j < 4; j++) {
    int d = (j - 2)*16 + llo;
    #pragma unroll
    for (int i = 0; i < 4; i++)
      #pragma unroll
      for (int r2 = 0; r2 < 4; r2++) {
        int r = i*16 + lhi*4 + r2;
        if (r < NTOK) Kh[r*36 + d] = f2bf(acc[j][i][r2] + bias[j]);
      }
  }
  // V epilogue -> Vt[d][token], ALL 64 tokens (finite, NaN-proofs PV)
  #pragma unroll
  for (int j = 4; j < 6; j++) {
    int d = (j - 4)*16 + llo;
    #pragma unroll
    for (int i = 0; i < 4; i++) {
      ushort4 pk;
      pk.x = f2bf(acc[j][i][0] + bias[j]);
      pk.y = f2bf(acc[j][i][1] + bias[j]);
      pk.z = f2bf(acc[j][i][2] + bias[j]);
      pk.w = f2bf(acc[j][i][3] + bias[j]);
      *(ushort4*)(Vh + d*68 + i*16 + lhi*4) = pk;
    }
  }

  // ---- QK^T (wave-private; per-wave DS ordering suffices) ----
  f32x4 s[4][4];
  #pragma unroll
  for (int i = 0; i < 4; i++)
    #pragma unroll
    for (int j = 0; j < 4; j++) s[i][j] = zv;

  {
    bf16x8 qa[4];
    #pragma unroll
    for (int i = 0; i < 4; i++) qa[i] = ld_frag(Qh + (i*16 + llo)*36 + lhi*8);
    #pragma unroll
    for (int j = 0; j < 4; j++) {
      bf16x8 kb = ld_frag(Kh + (j*16 + llo)*36 + lhi*8);
      #pragma unroll
      for (int i = 0; i < 4; i++) s[i][j] = MFMA(qa[i], kb, s[i][j]);
    }
  }

  // ---- + fused (mask + bias), c>=49 replaced (NaN-proof) ----
  {
    const float4* bmf4 = (const float4*)bmf + (size_t)(wi*4 + h)*16*64 + lane;
    #pragma unroll
    for (int j = 0; j < 4; j++) {
      bool cok = (j*16 + llo) < NTOK;
      #pragma unroll
      for (int i = 0; i < 4; i++) {
        float4 t = bmf4[(i*4 + j)*64];
        #pragma unroll
        for (int r2 = 0; r2 < 4; r2++) {
          float v = s[i][j][r2] + (&t.x)[r2];
          s[i][j][r2] = cok ? v : -1e30f;
        }
      }
    }
  }

  // ---- row softmax (row = 16 llo lanes x 4 j-regs) ----
  #pragma unroll
  for (int i = 0; i < 4; i++) {
    #pragma unroll
    for (int r2 = 0; r2 < 4; r2++) {
      float m = fmaxf(fmaxf(s[i][0][r2], s[i][1][r2]),
                      fmaxf(s[i][2][r2], s[i][3][r2]));
      #pragma unroll
      for (int off = 1; off < 16; off <<= 1) m = fmaxf(m, __shfl_xor(m, off, 64));
      float sum = 0.f;
      #pragma unroll
      for (int j = 0; j < 4; j++) {
        float p = __expf(s[i][j][r2] - m);
        s[i][j][r2] = p;
        sum += p;
      }
      #pragma unroll
      for (int off = 1; off < 16; off <<= 1) sum += __shfl_xor(sum, off, 64);
      float inv = 1.0f / sum;
      #pragma unroll
      for (int j = 0; j < 4; j++) s[i][j][r2] *= inv;
    }
  }

  // ---- P -> LDS (rows < 49; aliases Q|K) ----
  #pragma unroll
  for (int i = 0; i < 4; i++)
    #pragma unroll
    for (int r2 = 0; r2 < 4; r2++) {
      int r = i*16 + lhi*4 + r2;
      if (r < NTOK) {
        #pragma unroll
        for (int j = 0; j < 4; j++)
          Ph[r*72 + j*16 + llo] = f2bf(s[i][j][r2]);
      }
    }

  // ---- PV: O = P[*,64] @ V[64,32]; P cols>=49 are exact 0 ----
  f32x4 oacc[2][4];
  #pragma unroll
  for (int nt = 0; nt < 2; nt++)
    #pragma unroll
    for (int i = 0; i < 4; i++) oacc[nt][i] = zv;

  #pragma unroll
  for (int ks = 0; ks < 2; ks++) {
    bf16x8 pa[4];
    #pragma unroll
    for (int i = 0; i < 4; i++)
      pa[i] = ld_frag(Ph + (i*16 + llo)*72 + ks*32 + lhi*8);
    #pragma unroll
    for (int nt = 0; nt < 2; nt++) {
      bf16x8 vb = ld_frag(Vh + (nt*16 + llo)*68 + ks*32 + lhi*8);
      #pragma unroll
      for (int i = 0; i < 4; i++) oacc[nt][i] = MFMA(pa[i], vb, oacc[nt][i]);
    }
  }

  // ---- attn-out -> xo (rows < 49; aliases P) ----
  #pragma unroll
  for (int nt = 0; nt < 2; nt++)
    #pragma unroll
    for (int i = 0; i < 4; i++)
      #pragma unroll
      for (int r2 = 0; r2 < 4; r2++) {
        int r = i*16 + lhi*4 + r2;
        if (r < NTOK) XOh[r*36 + nt*16 + llo] = f2bf(oacc[nt][i][r2]);
      }

  __syncthreads();   // the ONE barrier: all heads' xo visible

  // ---- proj: out = xo(all heads) @ proj_w + proj_b ; wave h -> cols [h*32,+32) ----
  {
    f32x4 pacc[2][4];
    #pragma unroll
    for (int j = 0; j < 2; j++)
      #pragma unroll
      for (int i = 0; i < 4; i++) pacc[j][i] = zv;

    #pragma unroll
    for (int kt = 0; kt < 4; kt++) {
      bf16x8 a[4];
      #pragma unroll
      for (int i = 0; i < 4; i++)
        a[i] = ld_frag(smem + kt*SLOT + (i*16 + llo)*36 + lhi*8);
      #pragma unroll
      for (int j = 0; j < 2; j++) {
        int ct = h*2 + j;
        bf16x8 bw = ld_frag(wproj + (((kt*8 + ct)*64 + lane) << 3));
        #pragma unroll
        for (int i = 0; i < 4; i++) pacc[j][i] = MFMA(a[i], bw, pacc[j][i]);
      }
    }

    float* op = out + (size_t)b * (NTOK*DIMC);
    #pragma unroll
    for (int j = 0; j < 2; j++) {
      int c = (h*2 + j)*16 + llo;
      float pb = proj_b[c];
      #pragma unroll
      for (int i = 0; i < 4; i++)
        #pragma unroll
        for (int r2 = 0; r2 < 4; r2++) {
          int r = i*16 + lhi*4 + r2;
          if (r < NTOK) op[r*128 + c] = pacc[j][i][r2] + pb;
        }
    }
  }
}

extern "C" void kernel_launch(void* const* d_in, const int* in_sizes, int n_in,
                              void* d_out, int out_size, void* d_ws, size_t ws_size,
                              hipStream_t stream)
{
  const float* x          = (const float*)d_in[0];
  const float* mask       = (const float*)d_in[1];
  const float* qkv_w      = (const float*)d_in[2];
  const float* qkv_b      = (const float*)d_in[3];
  const float* proj_w     = (const float*)d_in[4];
  const float* proj_b     = (const float*)d_in[5];
  const float* bias_table = (const float*)d_in[6];
  const int*   rel_idx    = (const int*)d_in[7];
  float* out = (float*)d_out;

  unsigned short* wqkv  = (unsigned short*)d_ws;
  unsigned short* wproj = (unsigned short*)((char*)d_ws + WPROJ_OFF);
  float*          bmf   = (float*)((char*)d_ws + BMF_OFF);

  prep_kernel<<<1024, 256, 0, stream>>>(qkv_w, proj_w, bias_table, rel_idx, mask,
                                        wqkv, wproj, bmf);
  winattn_kernel<<<NBLK, 256, 0, stream>>>(x, qkv_b, proj_b, wqkv, wproj, bmf, out);
}

// Round 4
// 127.849 us; speedup vs baseline: 1.4451x; 1.0147x over previous
//
#include <hip/hip_runtime.h>

// ---------------- geometry ----------------
#define NTOK 49      // tokens per window
#define DIMC 128
#define NH   4
#define NWIN 64
#define NBLK 4096    // B_ = BATCH * NW

// ws layout (bytes):
//   wqkv : bf16[4*24*64*8] = 49152 el -> 98304 B @ 0
//   wproj: bf16[4*8*64*8]  = 16384 el -> 32768 B @ 98304
//   bmf  : f32 [64*4*16*256] = 1048576 el -> 4 MB @ 131072
//          fragment-ordered mask+bias, -1e30 baked for r>=49||c>=49
#define WPROJ_OFF 98304
#define BMF_OFF   131072

typedef unsigned short u16x8 __attribute__((ext_vector_type(8)));
typedef __bf16        bf16x8 __attribute__((ext_vector_type(8)));
typedef float         f32x4  __attribute__((ext_vector_type(4)));

__device__ __forceinline__ unsigned short f2bf(float f) {
  return __builtin_bit_cast(unsigned short, (__bf16)f);   // hw RNE cvt
}

__device__ __forceinline__ bf16x8 ld_frag(const unsigned short* p) {
  return __builtin_bit_cast(bf16x8, *(const u16x8*)p);
}

__device__ __forceinline__ bf16x8 pack_bf16x8(float4 lo, float4 hi) {
  bf16x8 r;
  r[0] = (__bf16)lo.x; r[1] = (__bf16)lo.y; r[2] = (__bf16)lo.z; r[3] = (__bf16)lo.w;
  r[4] = (__bf16)hi.x; r[5] = (__bf16)hi.y; r[6] = (__bf16)hi.z; r[7] = (__bf16)hi.w;
  return r;
}

#define MFMA(a, b, c) __builtin_amdgcn_mfma_f32_16x16x32_bf16(a, b, c, 0, 0, 0)

// ---------------- prep: pack weights + fragment-ordered mask/bias ----------------
__global__ void prep_kernel(const float* __restrict__ qkv_w,      // [128][384]
                            const float* __restrict__ proj_w,     // [128][128]
                            const float* __restrict__ bias_table, // [169][4]
                            const int*   __restrict__ rel_idx,    // [49*49]
                            const float* __restrict__ mask,       // [64][49][49]
                            unsigned short* __restrict__ wqkv,
                            unsigned short* __restrict__ wproj,
                            float* __restrict__ bmf)
{
  const int tid = blockIdx.x * blockDim.x + threadIdx.x;
  const int nth = gridDim.x * blockDim.x;

  for (int idx = tid; idx < 4*24*64*8; idx += nth) {
    int ii = idx & 7, lane = (idx >> 3) & 63, rest = idx >> 9;
    int ct = rest % 24, kt = rest / 24;
    int k = kt*32 + ((lane >> 4) << 3) + ii;
    int c = ct*16 + (lane & 15);
    wqkv[idx] = f2bf(qkv_w[k*384 + c]);
  }
  for (int idx = tid; idx < 4*8*64*8; idx += nth) {
    int ii = idx & 7, lane = (idx >> 3) & 63, rest = idx >> 9;
    int ct = rest & 7, kt = rest >> 3;
    int k = kt*32 + ((lane >> 4) << 3) + ii;
    int c = ct*16 + (lane & 15);
    wproj[idx] = f2bf(proj_w[k*128 + c]);
  }
  // bmf[(((wi*4+h)*16 + i*4+j)*64 + lane)*4 + r2]
  for (int idx = tid; idx < NWIN*NH*16*256; idx += nth) {
    int r2   = idx & 3;
    int lane = (idx >> 2) & 63;
    int ij   = (idx >> 8) & 15;
    int h    = (idx >> 12) & 3;
    int wi   = idx >> 14;
    int i = ij >> 2, j = ij & 3;
    int r = i*16 + ((lane >> 4) << 2) + r2;
    int c = j*16 + (lane & 15);
    float v = -1e30f;
    if (r < NTOK && c < NTOK)
      v = mask[wi*2401 + r*49 + c] + bias_table[rel_idx[r*49 + c]*4 + h];
    bmf[idx] = v;
  }
}

// ---------------- fused window attention (wave == head) ----------------
// LDS slot (u16): Q[49][36] @0 | K[49][36] @1764 | Vt[33][68] @3528 (row 32 = ones)
//   P[<49][72] aliases Q|K ; xo[<49][36] aliases P after PV
// SLOT = 1764+1764+2244 = 5772 ; smem padded to 24112 u16 so the nt=2
// sum-tile B-frags (Vt rows 33..47 = garbage, harmless) stay in-bounds.
#define SLOT 5772
__global__ __launch_bounds__(256, 3) void winattn_kernel(
    const float* __restrict__ x,
    const float* __restrict__ qkv_b,
    const float* __restrict__ proj_b,
    const unsigned short* __restrict__ wqkv,
    const unsigned short* __restrict__ wproj,
    const float* __restrict__ bmf,
    float* __restrict__ out)
{
  __shared__ __align__(16) unsigned short smem[24112];

  const int b    = blockIdx.x;
  const int wi   = b & (NWIN - 1);
  const int tid  = threadIdx.x;
  const int h    = tid >> 6;    // wave == head
  const int lane = tid & 63;
  const int lhi  = lane >> 4;   // 0..3
  const int llo  = lane & 15;   // 0..15

  unsigned short* slot = smem + h*SLOT;
  unsigned short* Qh  = slot;          // [49][36]
  unsigned short* Kh  = slot + 1764;   // [49][36]
  unsigned short* Vh  = slot + 3528;   // [33][68], row 32 = ones
  unsigned short* Ph  = slot;          // [<49][72]
  unsigned short* XOh = slot;          // [<49][36]

  const f32x4 zv = {0.f, 0.f, 0.f, 0.f};
  const float* xb = x + (size_t)b * (NTOK*DIMC);

  // ---- QKV GEMM: A-frags straight from global (f32 -> bf16 in-register) ----
  f32x4 acc[6][4];   // j: 0,1=q  2,3=k  4,5=v
  #pragma unroll
  for (int j = 0; j < 6; j++)
    #pragma unroll
    for (int i = 0; i < 4; i++) acc[j][i] = zv;

  #pragma unroll
  for (int kt = 0; kt < 4; kt++) {
    bf16x8 a[4];
    #pragma unroll
    for (int i = 0; i < 4; i++) {
      float4 lo = make_float4(0.f,0.f,0.f,0.f), hi = lo;
      int row = i*16 + llo;
      if (i < 3 || row < NTOK) {
        const float4* p = (const float4*)(xb + row*DIMC + kt*32 + lhi*8);
        lo = p[0]; hi = p[1];
      }
      a[i] = pack_bf16x8(lo, hi);
    }
    #pragma unroll
    for (int j = 0; j < 6; j++) {
      int ct = (j >> 1)*8 + h*2 + (j & 1);
      bf16x8 bw = ld_frag(wqkv + (((kt*24 + ct)*64 + lane) << 3));
      #pragma unroll
      for (int i = 0; i < 4; i++) acc[j][i] = MFMA(a[i], bw, acc[j][i]);
    }
  }

  float bias[6];
  #pragma unroll
  for (int j = 0; j < 6; j++)
    bias[j] = qkv_b[((j >> 1)*8 + h*2 + (j & 1))*16 + llo];

  const float scale = 0.17677669529663687f;  // 32^-0.5

  // Q epilogue (rows < 49)
  #pragma unroll
  for (int j = 0; j < 2; j++) {
    int d = j*16 + llo;
    #pragma unroll
    for (int i = 0; i < 4; i++)
      #pragma unroll
      for (int r2 = 0; r2 < 4; r2++) {
        int r = i*16 + lhi*4 + r2;
        if (r < NTOK) Qh[r*36 + d] = f2bf((acc[j][i][r2] + bias[j]) * scale);
      }
  }

  // ---- prefetch bmf (16 float4); K/V epilogues + QK^T hide the latency ----
  float4 bmv[16];
  {
    const float4* bmf4 = (const float4*)bmf + (size_t)(wi*4 + h)*16*64 + lane;
    #pragma unroll
    for (int t = 0; t < 16; t++) bmv[t] = bmf4[t*64];
  }

  // K epilogue
  #pragma unroll
  for (int j = 2; j < 4; j++) {
    int d = (j - 2)*16 + llo;
    #pragma unroll
    for (int i = 0; i < 4; i++)
      #pragma unroll
      for (int r2 = 0; r2 < 4; r2++) {
        int r = i*16 + lhi*4 + r2;
        if (r < NTOK) Kh[r*36 + d] = f2bf(acc[j][i][r2] + bias[j]);
      }
  }
  // V epilogue -> Vt[d][token], ALL 64 tokens
  #pragma unroll
  for (int j = 4; j < 6; j++) {
    int d = (j - 4)*16 + llo;
    #pragma unroll
    for (int i = 0; i < 4; i++) {
      ushort4 pk;
      pk.x = f2bf(acc[j][i][0] + bias[j]);
      pk.y = f2bf(acc[j][i][1] + bias[j]);
      pk.z = f2bf(acc[j][i][2] + bias[j]);
      pk.w = f2bf(acc[j][i][3] + bias[j]);
      *(ushort4*)(Vh + d*68 + i*16 + lhi*4) = pk;
    }
  }
  // ones row (d=32) for MFMA row-sums
  Vh[32*68 + lane] = 0x3F80;   // bf16(1.0)

  // ---- QK^T (wave-private) ----
  f32x4 s[4][4];
  #pragma unroll
  for (int i = 0; i < 4; i++)
    #pragma unroll
    for (int j = 0; j < 4; j++) s[i][j] = zv;

  {
    bf16x8 qa[4];
    #pragma unroll
    for (int i = 0; i < 4; i++) qa[i] = ld_frag(Qh + (i*16 + llo)*36 + lhi*8);
    #pragma unroll
    for (int j = 0; j < 4; j++) {
      bf16x8 kb = ld_frag(Kh + (j*16 + llo)*36 + lhi*8);
      #pragma unroll
      for (int i = 0; i < 4; i++) s[i][j] = MFMA(qa[i], kb, s[i][j]);
    }
  }

  // ---- + fused (mask+bias); exp WITHOUT max-subtraction (|logits| small,
  //      masked/pad entries -1e30 -> exp 0); P~ unnormalized to LDS ----
  #pragma unroll
  for (int j = 0; j < 4; j++) {
    bool cok = (j*16 + llo) < NTOK;
    #pragma unroll
    for (int i = 0; i < 4; i++) {
      float4 t = bmv[i*4 + j];
      #pragma unroll
      for (int r2 = 0; r2 < 4; r2++) {
        float v = s[i][j][r2] + (&t.x)[r2];
        s[i][j][r2] = __expf(cok ? v : -1e30f);
      }
    }
  }

  // ---- P~ -> LDS (rows < 49; aliases Q|K) ----
  #pragma unroll
  for (int i = 0; i < 4; i++)
    #pragma unroll
    for (int r2 = 0; r2 < 4; r2++) {
      int r = i*16 + lhi*4 + r2;
      if (r < NTOK) {
        #pragma unroll
        for (int j = 0; j < 4; j++)
          Ph[r*72 + j*16 + llo] = f2bf(s[i][j][r2]);
      }
    }

  // ---- PV + row-sum tile: O = P~ @ V ; D[.,32] = row sums (ones column) ----
  f32x4 oacc[2][4], osum[4];
  #pragma unroll
  for (int i = 0; i < 4; i++) { oacc[0][i] = zv; oacc[1][i] = zv; osum[i] = zv; }

  #pragma unroll
  for (int ks = 0; ks < 2; ks++) {
    bf16x8 pa[4];
    #pragma unroll
    for (int i = 0; i < 4; i++)
      pa[i] = ld_frag(Ph + (i*16 + llo)*72 + ks*32 + lhi*8);
    #pragma unroll
    for (int nt = 0; nt < 3; nt++) {
      bf16x8 vb = ld_frag(Vh + (nt*16 + llo)*68 + ks*32 + lhi*8);
      #pragma unroll
      for (int i = 0; i < 4; i++) {
        if (nt < 2) oacc[nt][i] = MFMA(pa[i], vb, oacc[nt][i]);
        else        osum[i]     = MFMA(pa[i], vb, osum[i]);
      }
    }
  }

  // ---- deferred normalization: broadcast row-sum (col 32 lives in llo=0) ----
  #pragma unroll
  for (int i = 0; i < 4; i++)
    #pragma unroll
    for (int r2 = 0; r2 < 4; r2++) {
      float sm  = __shfl(osum[i][r2], lane & 48, 64);
      float inv = __builtin_amdgcn_rcpf(sm);
      oacc[0][i][r2] *= inv;
      oacc[1][i][r2] *= inv;
    }

  // ---- attn-out -> xo (rows < 49; aliases P) ----
  #pragma unroll
  for (int nt = 0; nt < 2; nt++)
    #pragma unroll
    for (int i = 0; i < 4; i++)
      #pragma unroll
      for (int r2 = 0; r2 < 4; r2++) {
        int r = i*16 + lhi*4 + r2;
        if (r < NTOK) XOh[r*36 + nt*16 + llo] = f2bf(oacc[nt][i][r2]);
      }

  __syncthreads();   // the ONE barrier: all heads' xo visible

  // ---- proj: out = xo(all heads) @ proj_w + proj_b ; wave h -> cols [h*32,+32) ----
  {
    f32x4 pacc[2][4];
    #pragma unroll
    for (int j = 0; j < 2; j++)
      #pragma unroll
      for (int i = 0; i < 4; i++) pacc[j][i] = zv;

    #pragma unroll
    for (int kt = 0; kt < 4; kt++) {
      bf16x8 a[4];
      #pragma unroll
      for (int i = 0; i < 4; i++)
        a[i] = ld_frag(smem + kt*SLOT + (i*16 + llo)*36 + lhi*8);
      #pragma unroll
      for (int j = 0; j < 2; j++) {
        int ct = h*2 + j;
        bf16x8 bw = ld_frag(wproj + (((kt*8 + ct)*64 + lane) << 3));
        #pragma unroll
        for (int i = 0; i < 4; i++) pacc[j][i] = MFMA(a[i], bw, pacc[j][i]);
      }
    }

    float* op = out + (size_t)b * (NTOK*DIMC);
    #pragma unroll
    for (int j = 0; j < 2; j++) {
      int c = (h*2 + j)*16 + llo;
      float pb = proj_b[c];
      #pragma unroll
      for (int i = 0; i < 4; i++)
        #pragma unroll
        for (int r2 = 0; r2 < 4; r2++) {
          int r = i*16 + lhi*4 + r2;
          if (r < NTOK) op[r*128 + c] = pacc[j][i][r2] + pb;
        }
    }
  }
}

extern "C" void kernel_launch(void* const* d_in, const int* in_sizes, int n_in,
                              void* d_out, int out_size, void* d_ws, size_t ws_size,
                              hipStream_t stream)
{
  const float* x          = (const float*)d_in[0];
  const float* mask       = (const float*)d_in[1];
  const float* qkv_w      = (const float*)d_in[2];
  const float* qkv_b      = (const float*)d_in[3];
  const float* proj_w     = (const float*)d_in[4];
  const float* proj_b     = (const float*)d_in[5];
  const float* bias_table = (const float*)d_in[6];
  const int*   rel_idx    = (const int*)d_in[7];
  float* out = (float*)d_out;

  unsigned short* wqkv  = (unsigned short*)d_ws;
  unsigned short* wproj = (unsigned short*)((char*)d_ws + WPROJ_OFF);
  float*          bmf   = (float*)((char*)d_ws + BMF_OFF);

  prep_kernel<<<1024, 256, 0, stream>>>(qkv_w, proj_w, bias_table, rel_idx, mask,
                                        wqkv, wproj, bmf);
  winattn_kernel<<<NBLK, 256, 0, stream>>>(x, qkv_b, proj_b, wqkv, wproj, bmf, out);
}